// Round 3
// baseline (122.065 us; speedup 1.0000x reference)
//
#include <hip/hip_runtime.h>

// CRF loss: A=8, S=200, B=64, T=32. scores (A,S,B,T,T) f32, targets (A,S,B) i32,
// mask (S,B) bool, a_mask (A,B) bool -- bool width (u8 vs i32) runtime-detected.
// One wave per (a,b) chain; float4 tile loads, depth-7 register prefetch;
// log2-domain recentered forward recursion (no per-step max tracking).
constexpr int A_ = 8, S_ = 200, B_ = 64, T_ = 32;
constexpr int START_TAG = 30, END_TAG = 31;
#define LOG2E 1.44269504088896340736f
#define LN2   0.69314718055994530942f

#if __has_builtin(__builtin_amdgcn_exp2f)
#define EXP2F(x) __builtin_amdgcn_exp2f(x)
#else
#define EXP2F(x) __expf((x) * LN2)
#endif
#if __has_builtin(__builtin_amdgcn_logf)
#define LOG2F_(x) __builtin_amdgcn_logf(x)
#else
#define LOG2F_(x) (__logf(x) * LOG2E)
#endif

__device__ __forceinline__ int load_flag(const void* p, bool u8, int idx) {
    return u8 ? (int)((const unsigned char*)p)[idx] : ((const int*)p)[idx];
}

struct TileBuf { float4 q0, q1, q2, q3; float g; };

__global__ __launch_bounds__(64)
void crf_loss_kernel(const float* __restrict__ scores,
                     const int* __restrict__ targets,
                     const void* __restrict__ mask,
                     const void* __restrict__ amask,
                     float* __restrict__ out)
{
    const int chain = blockIdx.x;          // 0..511
    const int a = chain >> 6;
    const int b = chain & (B_ - 1);
    const int lane = threadIdx.x;          // 0..63

    // bool width detect: mask row 0 is all-true. int view: 1 -> int32, 0x01010101 -> uint8
    const bool bool_u8 = (((const int*)mask)[0] != 1);
    if (!load_flag(amask, bool_u8, a * B_ + b)) return;

    __shared__ int tg_lds[S_];
    __shared__ float part_lds[T_];         // partition in log2 units, recentered (<= 0)

    // ---- first false mask index L (prefix mask) ----
    int L = S_;
    for (int base = 0; base < S_; base += 64) {
        int i = base + lane;
        int mv = (i < S_) ? load_flag(mask, bool_u8, i * B_ + b) : 1;
        unsigned long long bal = __ballot(mv == 0);
        if (bal != 0ull && L == S_) L = base + (int)__builtin_ctzll(bal);
    }

    for (int i = lane; i < S_; i += 64)
        tg_lds[i] = targets[((size_t)a * S_ + i) * B_ + b];

    const size_t s_stride = (size_t)B_ * T_ * T_;   // 65536 floats per s-step
    const float* cb = scores + ((size_t)a * S_ * B_ + b) * (T_ * T_);

    // ---- step 0 init: part2[t] = scores[a,0,b,START,t] * log2e ----
    if (lane < 32) part_lds[lane] = cb[START_TAG * T_ + lane] * LOG2E;
    float C2 = 0.0f;                       // running log2-offset (wave-uniform)
    float tg = (L > 0) ? cb[tg_lds[0]] : 0.0f;   // gold energy (ln units)

    const int fl = lane >> 3;              // f sub-index 0..7 (f = c*8 + fl)
    // lane's 4 t values: t = 4*(lane&7) + j

    // Load tile for step SIDX: lane l, chunk c covers floats c*256 + 4l + j.
#define LOADT(BUF, SIDX) do {                                            \
        const int sc_ = (SIDX);                                          \
        if (sc_ < L) {                                                   \
            const float* p_ = cb + (size_t)sc_ * s_stride;               \
            const float4* p4_ = (const float4*)p_;                       \
            BUF.g  = p_[tg_lds[sc_]];                                    \
            BUF.q0 = p4_[lane];                                          \
            BUF.q1 = p4_[64 + lane];                                     \
            BUF.q2 = p4_[128 + lane];                                    \
            BUF.q3 = p4_[192 + lane];                                    \
        }                                                                \
    } while (0)

    // One scan step in log2 domain:
    //   S_t = sum_f exp2(tile[f][t]*log2e + part2[f]);  raw_t = log2(S_t)
    //   mx = max_t raw; part2[t] = raw_t - mx; C2 += mx; tg += gather
#define STEPX(BUF) do {                                                  \
        float p0_ = part_lds[fl],      p1_ = part_lds[8 + fl];           \
        float p2_ = part_lds[16 + fl], p3_ = part_lds[24 + fl];          \
        float s0_ = EXP2F(fmaf(BUF.q0.x, LOG2E, p0_))                    \
                  + EXP2F(fmaf(BUF.q1.x, LOG2E, p1_))                    \
                  + EXP2F(fmaf(BUF.q2.x, LOG2E, p2_))                    \
                  + EXP2F(fmaf(BUF.q3.x, LOG2E, p3_));                   \
        float s1_ = EXP2F(fmaf(BUF.q0.y, LOG2E, p0_))                    \
                  + EXP2F(fmaf(BUF.q1.y, LOG2E, p1_))                    \
                  + EXP2F(fmaf(BUF.q2.y, LOG2E, p2_))                    \
                  + EXP2F(fmaf(BUF.q3.y, LOG2E, p3_));                   \
        float s2_ = EXP2F(fmaf(BUF.q0.z, LOG2E, p0_))                    \
                  + EXP2F(fmaf(BUF.q1.z, LOG2E, p1_))                    \
                  + EXP2F(fmaf(BUF.q2.z, LOG2E, p2_))                    \
                  + EXP2F(fmaf(BUF.q3.z, LOG2E, p3_));                   \
        float s3_ = EXP2F(fmaf(BUF.q0.w, LOG2E, p0_))                    \
                  + EXP2F(fmaf(BUF.q1.w, LOG2E, p1_))                    \
                  + EXP2F(fmaf(BUF.q2.w, LOG2E, p2_))                    \
                  + EXP2F(fmaf(BUF.q3.w, LOG2E, p3_));                   \
        s0_ += __shfl_xor(s0_, 8);  s1_ += __shfl_xor(s1_, 8);           \
        s2_ += __shfl_xor(s2_, 8);  s3_ += __shfl_xor(s3_, 8);           \
        s0_ += __shfl_xor(s0_, 16); s1_ += __shfl_xor(s1_, 16);          \
        s2_ += __shfl_xor(s2_, 16); s3_ += __shfl_xor(s3_, 16);          \
        s0_ += __shfl_xor(s0_, 32); s1_ += __shfl_xor(s1_, 32);          \
        s2_ += __shfl_xor(s2_, 32); s3_ += __shfl_xor(s3_, 32);          \
        float r0_ = LOG2F_(s0_), r1_ = LOG2F_(s1_);                      \
        float r2_ = LOG2F_(s2_), r3_ = LOG2F_(s3_);                      \
        float mx_ = fmaxf(fmaxf(r0_, r1_), fmaxf(r2_, r3_));             \
        mx_ = fmaxf(mx_, __shfl_xor(mx_, 1));                            \
        mx_ = fmaxf(mx_, __shfl_xor(mx_, 2));                            \
        mx_ = fmaxf(mx_, __shfl_xor(mx_, 4));                            \
        C2 += mx_;                                                       \
        if (lane < 8) {                                                  \
            float4 w4_;                                                  \
            w4_.x = r0_ - mx_; w4_.y = r1_ - mx_;                        \
            w4_.z = r2_ - mx_; w4_.w = r3_ - mx_;                        \
            *(float4*)&part_lds[4 * lane] = w4_;                         \
        }                                                                \
        tg += BUF.g;                                                     \
    } while (0)

    // ---- main scan s = 1..L-1, depth-7 register prefetch (8 rotating buffers) ----
    if (L > 1) {
        TileBuf t0, t1, t2, t3, t4, t5, t6, t7;
        LOADT(t0, 1); LOADT(t1, 2); LOADT(t2, 3); LOADT(t3, 4);
        LOADT(t4, 5); LOADT(t5, 6); LOADT(t6, 7);
        for (int s = 1; s < L; s += 8) {
            LOADT(t7, s + 7);  STEPX(t0);
            if (s + 1 >= L) break;
            LOADT(t0, s + 8);  STEPX(t1);
            if (s + 2 >= L) break;
            LOADT(t1, s + 9);  STEPX(t2);
            if (s + 3 >= L) break;
            LOADT(t2, s + 10); STEPX(t3);
            if (s + 4 >= L) break;
            LOADT(t3, s + 11); STEPX(t4);
            if (s + 5 >= L) break;
            LOADT(t4, s + 12); STEPX(t5);
            if (s + 6 >= L) break;
            LOADT(t5, s + 13); STEPX(t6);
            if (s + 7 >= L) break;
            LOADT(t6, s + 14); STEPX(t7);
        }
    }

    // ---- epilogue: logZ = (C2 + part2[END_TAG]) * ln2 ----
    float logZ = (C2 + part_lds[END_TAG]) * LN2;
    if (lane == 0)
        atomicAdd(out, (logZ - tg) * (1.0f / (float)B_));
}

extern "C" void kernel_launch(void* const* d_in, const int* in_sizes, int n_in,
                              void* d_out, int out_size, void* d_ws, size_t ws_size,
                              hipStream_t stream) {
    const float* scores = (const float*)d_in[0];
    const int* targets  = (const int*)d_in[1];
    const void* mask    = d_in[2];
    const void* amask   = d_in[3];
    float* out = (float*)d_out;

    hipMemsetAsync(out, 0, sizeof(float), stream);
    crf_loss_kernel<<<dim3(A_ * B_), dim3(64), 0, stream>>>(
        scores, targets, mask, amask, out);
}

// Round 4
// 101.097 us; speedup vs baseline: 1.2074x; 1.2074x over previous
//
#include <hip/hip_runtime.h>

// CRF loss: A=8, S=200, B=64, T=32. scores (A,S,B,T,T) f32, targets (A,S,B) i32,
// mask (S,B) bool, a_mask (A,B) bool -- bool width (u8 vs i32) runtime-detected.
// One wave per (a,b) chain. LINEAR-domain forward recursion: w_new[t] =
// sum_f exp(score[f][t]) * w[f]; exp() is off the serial path; exponent renorm
// every 4 steps. Lane layout: lane = (t, half); 16 coalesced row loads/step,
// depth-3 register prefetch.
constexpr int A_ = 8, S_ = 200, B_ = 64, T_ = 32;
constexpr int START_TAG = 30, END_TAG = 31;
#define LOG2E 1.44269504088896340736f
#define LN2   0.69314718055994530942f

#if __has_builtin(__builtin_amdgcn_exp2f)
#define EXP2F(x) __builtin_amdgcn_exp2f(x)
#else
#define EXP2F(x) __expf((x) * LN2)
#endif

__device__ __forceinline__ int load_flag(const void* p, bool u8, int idx) {
    return u8 ? (int)((const unsigned char*)p)[idx] : ((const int*)p)[idx];
}

struct TileBuf { float r[16]; float g; };

__global__ __launch_bounds__(64)
void crf_loss_kernel(const float* __restrict__ scores,
                     const int* __restrict__ targets,
                     const void* __restrict__ mask,
                     const void* __restrict__ amask,
                     float* __restrict__ out)
{
    const int chain = blockIdx.x;          // 0..511
    const int a = chain >> 6;
    const int b = chain & (B_ - 1);
    const int lane = threadIdx.x;          // 0..63
    const int t = lane & 31;
    const int fbase = (lane >> 5) << 4;    // 0 or 16

    // bool width detect: mask row 0 is all-true. int view: 1 -> int32, 0x01010101 -> uint8
    const bool bool_u8 = (((const int*)mask)[0] != 1);
    if (!load_flag(amask, bool_u8, a * B_ + b)) return;

    __shared__ int tg_lds[S_];
    __shared__ __align__(16) float wlds[T_];   // linear partition w[t], renormed

    // ---- first false mask index L (prefix mask) ----
    int L = S_;
    for (int base = 0; base < S_; base += 64) {
        int i = base + lane;
        int mv = (i < S_) ? load_flag(mask, bool_u8, i * B_ + b) : 1;
        unsigned long long bal = __ballot(mv == 0);
        if (bal != 0ull && L == S_) L = base + (int)__builtin_ctzll(bal);
    }

    for (int i = lane; i < S_; i += 64)
        tg_lds[i] = targets[((size_t)a * S_ + i) * B_ + b];

    const size_t s_stride = (size_t)B_ * T_ * T_;   // 65536 floats per s-step
    const float* cb = scores + ((size_t)a * S_ * B_ + b) * (T_ * T_);

    // ---- step 0: w[t] = exp(scores[a,0,b,START,t]) ----
    float wcur = EXP2F(cb[START_TAG * T_ + t] * LOG2E);
    if (lane < 32) wlds[lane] = wcur;
    float C2 = 0.0f;                       // accumulated log2 offset (wave-uniform)
    float tg = (L > 0) ? cb[tg_lds[0]] : 0.0f;   // gold-path energy (ln units)

    // Load raw tile rows for step SIDX: inst i reads rows (fbase+i), 2x128B coalesced.
#define LOADT(BUF, SIDX) do {                                            \
        const int sc_ = (SIDX);                                          \
        if (sc_ < L) {                                                   \
            const float* p_ = cb + (size_t)sc_ * s_stride;               \
            BUF.g = p_[tg_lds[sc_]];                                     \
            _Pragma("unroll")                                            \
            for (int i_ = 0; i_ < 16; ++i_)                              \
                BUF.r[i_] = p_[((fbase + i_) << 5) | t];                 \
        }                                                                \
    } while (0)

    // One linear-domain step: wcur = sum_f exp2(r[f]*log2e) * w[f]; both halves
    // combined via one xor-32 shuffle; lanes<32 publish w to LDS for next step.
#define STEPX(BUF) do {                                                  \
        float4 wa_ = *(const float4*)&wlds[fbase];                       \
        float4 wb_ = *(const float4*)&wlds[fbase + 4];                   \
        float4 wc_ = *(const float4*)&wlds[fbase + 8];                   \
        float4 wd_ = *(const float4*)&wlds[fbase + 12];                  \
        float e_[16];                                                    \
        _Pragma("unroll")                                                \
        for (int i_ = 0; i_ < 16; ++i_)                                  \
            e_[i_] = EXP2F(BUF.r[i_] * LOG2E);                           \
        float s0_ = fmaf(e_[3], wa_.w, fmaf(e_[2], wa_.z,                \
                    fmaf(e_[1], wa_.y, e_[0] * wa_.x)));                 \
        float s1_ = fmaf(e_[7], wb_.w, fmaf(e_[6], wb_.z,                \
                    fmaf(e_[5], wb_.y, e_[4] * wb_.x)));                 \
        float s2_ = fmaf(e_[11], wc_.w, fmaf(e_[10], wc_.z,              \
                    fmaf(e_[9], wc_.y, e_[8] * wc_.x)));                 \
        float s3_ = fmaf(e_[15], wd_.w, fmaf(e_[14], wd_.z,              \
                    fmaf(e_[13], wd_.y, e_[12] * wd_.x)));               \
        float s_ = (s0_ + s1_) + (s2_ + s3_);                            \
        s_ += __shfl_xor(s_, 32);                                        \
        wcur = s_;                                                       \
        if (lane < 32) wlds[lane] = s_;                                  \
        tg += BUF.g;                                                     \
    } while (0)

    // Exponent renorm (exact power of 2): every 4 steps. Growth <= 2^14/step
    // worst-case, so w stays well inside f32 range between renorms.
#define RENORM do {                                                      \
        float m_ = wcur;                                                 \
        m_ = fmaxf(m_, __shfl_xor(m_, 1));                               \
        m_ = fmaxf(m_, __shfl_xor(m_, 2));                               \
        m_ = fmaxf(m_, __shfl_xor(m_, 4));                               \
        m_ = fmaxf(m_, __shfl_xor(m_, 8));                               \
        m_ = fmaxf(m_, __shfl_xor(m_, 16));                              \
        int eb_ = (__float_as_int(m_) >> 23) & 0xff;                     \
        C2 += (float)(eb_ - 127);                                        \
        float sc_ = __int_as_float((254 - eb_) << 23);                   \
        wcur *= sc_;                                                     \
        if (lane < 32) wlds[lane] = wcur;                                \
    } while (0)

    // ---- main scan s = 1..L-1, depth-3 prefetch, renorm once per 4 steps ----
    if (L > 1) {
        TileBuf t0, t1, t2, t3;
        t0.g = t1.g = t2.g = t3.g = 0.0f;
        LOADT(t0, 1); LOADT(t1, 2); LOADT(t2, 3);
        for (int s = 1; s < L; s += 4) {
            LOADT(t3, s + 3); STEPX(t0);
            if (s + 1 >= L) break;
            LOADT(t0, s + 4); STEPX(t1);
            if (s + 2 >= L) break;
            LOADT(t1, s + 5); STEPX(t2);
            if (s + 3 >= L) break;
            LOADT(t2, s + 6); STEPX(t3);
            RENORM;
        }
    }

    // ---- epilogue: logZ = ln(w[END_TAG]) + C2*ln2 ----
    float wend = __shfl(wcur, END_TAG);
    float logZ = __logf(wend) + C2 * LN2;
    if (lane == 0)
        atomicAdd(out, (logZ - tg) * (1.0f / (float)B_));
}

extern "C" void kernel_launch(void* const* d_in, const int* in_sizes, int n_in,
                              void* d_out, int out_size, void* d_ws, size_t ws_size,
                              hipStream_t stream) {
    const float* scores = (const float*)d_in[0];
    const int* targets  = (const int*)d_in[1];
    const void* mask    = d_in[2];
    const void* amask   = d_in[3];
    float* out = (float*)d_out;

    hipMemsetAsync(out, 0, sizeof(float), stream);
    crf_loss_kernel<<<dim3(A_ * B_), dim3(64), 0, stream>>>(
        scores, targets, mask, amask, out);
}